// Round 1
// baseline (329.683 us; speedup 1.0000x reference)
//
#include <hip/hip_runtime.h>
#include <hip/hip_bf16.h>

typedef __attribute__((ext_vector_type(8))) short bf16x8;   // 8 bf16 = 4 VGPR (MFMA A/B frag)
typedef __attribute__((ext_vector_type(4))) float f32x4;    // MFMA C/D frag

#define DEVI __device__ __forceinline__

constexpr int SEQ_   = 2048;
constexpr int HEADS  = 16;
constexpr int DHEAD  = 64;
constexpr int DMODEL = 1024;

DEVI unsigned short f2bf(float x) {
  __hip_bfloat16 h = __float2bfloat16(x);   // RNE
  return __builtin_bit_cast(unsigned short, h);
}

DEVI f32x4 MFMA(bf16x8 a, bf16x8 b, f32x4 c) {
  return __builtin_amdgcn_mfma_f32_16x16x32_bf16(a, b, c, 0, 0, 0);
}

// ---------------------------------------------------------------- convert ---
__global__ void conv3_kernel(const float* s0, const float* s1, const float* s2,
                             unsigned short* d0, unsigned short* d1, unsigned short* d2,
                             int n) {
  const float* s = (blockIdx.y == 0) ? s0 : (blockIdx.y == 1) ? s1 : s2;
  unsigned short* d = (blockIdx.y == 0) ? d0 : (blockIdx.y == 1) ? d1 : d2;
  int i = (blockIdx.x * 256 + threadIdx.x) * 8;
  if (i >= n) return;
  const float4* p = (const float4*)(s + i);
  float4 v0 = p[0], v1 = p[1];
  union { unsigned short u[8]; bf16x8 v; } t;
  t.u[0] = f2bf(v0.x); t.u[1] = f2bf(v0.y); t.u[2] = f2bf(v0.z); t.u[3] = f2bf(v0.w);
  t.u[4] = f2bf(v1.x); t.u[5] = f2bf(v1.y); t.u[6] = f2bf(v1.z); t.u[7] = f2bf(v1.w);
  *(bf16x8*)(d + i) = t.v;
}

// ------------------------------------------------------------- projection ---
// C[n][e] = sum_d X[n][d]*W[e][d] + bias[e], M=4096 N=1024 K=1024, both
// operands k-contiguous (einsum 'bsd,ed->bse' means B^T layout is natural).
// Output written bf16 in head-major layout: ((b*H + h)*S + s)*64 + d.
__global__ __launch_bounds__(256) void proj_kernel(const unsigned short* __restrict__ X,
                                                   const unsigned short* __restrict__ W,
                                                   const float* __restrict__ bias,
                                                   unsigned short* __restrict__ out) {
  __shared__ unsigned short Abuf[2][128 * 32];   // [row][k] rows of 64B -> conflict-free b128 reads
  __shared__ unsigned short Bbuf[2][128 * 32];
  const int tid  = threadIdx.x;
  const int lane = tid & 63, wv = tid >> 6;
  const int q = lane >> 4, r = lane & 15;
  const int wrow = wv >> 1, wcol = wv & 1;       // 2x2 waves, 64x64 out each
  const int rowA0 = blockIdx.x * 128, colB0 = blockIdx.y * 128;

  const char* Ag = (const char*)(X + (size_t)rowA0 * DMODEL);
  const char* Bg = (const char*)(W + (size_t)colB0 * DMODEL);

  f32x4 acc[4][4] = {};

  auto stage = [&](int ks, int buf) {
    const int koff = ks * 64;                    // byte offset of k-chunk within a row
#pragma unroll
    for (int i = 0; i < 2; ++i) {
      const int b   = (i * 256 + tid) * 16;      // byte in 8KB tile
      const int row = b >> 6, col = b & 63;
      __builtin_amdgcn_global_load_lds(
          (const __attribute__((address_space(1))) void*)(Ag + (size_t)row * (DMODEL * 2) + koff + col),
          (__attribute__((address_space(3))) void*)((char*)&Abuf[buf][0] + i * 4096 + wv * 1024),
          16, 0, 0);
      __builtin_amdgcn_global_load_lds(
          (const __attribute__((address_space(1))) void*)(Bg + (size_t)row * (DMODEL * 2) + koff + col),
          (__attribute__((address_space(3))) void*)((char*)&Bbuf[buf][0] + i * 4096 + wv * 1024),
          16, 0, 0);
    }
  };

  stage(0, 0);
  for (int ks = 0; ks < 32; ++ks) {
    __syncthreads();                             // drains vmcnt -> staged tile ready
    if (ks + 1 < 32) stage(ks + 1, (ks + 1) & 1);
    const unsigned short* A  = &Abuf[ks & 1][0];
    const unsigned short* Bt = &Bbuf[ks & 1][0];
    bf16x8 af[4], bfr[4];
#pragma unroll
    for (int t = 0; t < 4; ++t) {
      af[t]  = *(const bf16x8*)(A  + (wrow * 64 + t * 16 + r) * 32 + q * 8);
      bfr[t] = *(const bf16x8*)(Bt + (wcol * 64 + t * 16 + r) * 32 + q * 8);
    }
#pragma unroll
    for (int m = 0; m < 4; ++m)
#pragma unroll
      for (int n = 0; n < 4; ++n)
        acc[m][n] = MFMA(af[m], bfr[n], acc[m][n]);
  }

  // epilogue: bias + bf16 + head-major store (C layout: col=lane&15, row=(lane>>4)*4+reg)
#pragma unroll
  for (int m = 0; m < 4; ++m) {
#pragma unroll
    for (int n = 0; n < 4; ++n) {
      const int e  = colB0 + wcol * 64 + n * 16 + r;
      const float bv = bias[e];
      const int h = e >> 6, dd = e & 63;
#pragma unroll
      for (int j = 0; j < 4; ++j) {
        const int nrow = rowA0 + wrow * 64 + m * 16 + q * 4 + j;
        const int bb = nrow >> 11, ss = nrow & 2047;
        out[((size_t)(bb * HEADS + h) * SEQ_ + ss) * DHEAD + dd] = f2bf(acc[m][n][j] + bv);
      }
    }
  }
}

// -------------------------------------------------------------- transpose ---
// (bh, s, d) -> (bh, d, s) so PV's B operand is t-contiguous.
__global__ __launch_bounds__(256) void transpose_v_kernel(const unsigned short* __restrict__ vin,
                                                          unsigned short* __restrict__ vout) {
  __shared__ unsigned short t[64][65];
  const int s0 = blockIdx.x * 64;
  const unsigned short* src = vin  + (size_t)blockIdx.y * SEQ_ * DHEAD + (size_t)s0 * DHEAD;
  unsigned short*       dst = vout + (size_t)blockIdx.y * DHEAD * SEQ_ + s0;
  const int row = threadIdx.x >> 2, seg = (threadIdx.x & 3) * 16;
  unsigned short val[16];
  *(bf16x8*)&val[0] = *(const bf16x8*)(src + row * 64 + seg);
  *(bf16x8*)&val[8] = *(const bf16x8*)(src + row * 64 + seg + 8);
#pragma unroll
  for (int j = 0; j < 16; ++j) t[row][seg + j] = val[j];
  __syncthreads();
#pragma unroll
  for (int j = 0; j < 16; ++j) val[j] = t[seg + j][row];
  *(bf16x8*)(dst + (size_t)row * SEQ_ + seg)     = *(bf16x8*)&val[0];
  *(bf16x8*)(dst + (size_t)row * SEQ_ + seg + 8) = *(bf16x8*)&val[8];
}

// -------------------------------------------------------------- attention ---
// Grid: x = q-tile (16, reversed for load balance), y = b*H+h (32).
// Block = 4 waves; wave w owns rows [S0+32w, S0+32w+32).
// Srel[s,t] = QEr[s, S-1+t-s]; per K-tile we need l in [lb, lb+62],
// lb = S-32-s0+t0; left 32-wide half is previous iteration's right half.
__global__ __launch_bounds__(256) void attn_kernel(const unsigned short* __restrict__ qb,
                                                   const unsigned short* __restrict__ kb,
                                                   const unsigned short* __restrict__ vT,
                                                   const unsigned short* __restrict__ Er,
                                                   float* __restrict__ out) {
  __shared__ unsigned short k_lds[2][32][32];    // [d-chunk][t][d%32] -> 64B rows, conflict-free
  __shared__ unsigned short v_lds[64][32];       // [d][t]
  __shared__ float          qer_w[4][32][68];    // per-wave QEr window [s_local][l_local], padded
  __shared__ unsigned short p_lds[4][32][40];    // per-wave P [s_local][t_local], stride 40

  const int tid = threadIdx.x;
  const int lane = tid & 63, wv = tid >> 6;
  const int q = lane >> 4, r = lane & 15;
  const int bh = blockIdx.y;
  const int qtile = (int)(gridDim.x - 1) - (int)blockIdx.x;  // big tiles dispatched first
  const int S0 = qtile * 128;
  const int s0 = S0 + wv * 32;

  const unsigned short* qbh = qb + (size_t)bh * SEQ_ * DHEAD;
  const unsigned short* kbh = kb + (size_t)bh * SEQ_ * DHEAD;
  const unsigned short* vbh = vT + (size_t)bh * DHEAD * SEQ_;

  const f32x4 zero4 = {0.f, 0.f, 0.f, 0.f};

  // q fragments: rows s0+rt*16+r, k = kc*32 + q*8 (A operand, k-contiguous)
  bf16x8 qf[2][2];
#pragma unroll
  for (int rt = 0; rt < 2; ++rt)
#pragma unroll
    for (int kc = 0; kc < 2; ++kc)
      qf[rt][kc] = *(const bf16x8*)(qbh + (size_t)(s0 + rt * 16 + r) * DHEAD + kc * 32 + q * 8);

  f32x4 oacc[2][4] = {};
  f32x4 qerL[2][2];
  float mrow[2][4], lrow[2][4];
#pragma unroll
  for (int rt = 0; rt < 2; ++rt)
#pragma unroll
    for (int j = 0; j < 4; ++j) { mrow[rt][j] = -1e30f; lrow[rt][j] = 0.f; }

  const int nIter = qtile * 4 + 4;
  for (int it = 0; it < nIter; ++it) {
    const int t0 = it * 32;
    {  // stage K (4KB, chunked) and V^T (4KB) tiles; 16B per thread each
      const int b = tid * 16;
      const int kc = b >> 11, rem = b & 2047;
      const int tt = rem >> 6, db = rem & 63;
      *(bf16x8*)((char*)&k_lds[0][0][0] + b) =
          *(const bf16x8*)((const char*)kbh + (size_t)(t0 + tt) * 128 + kc * 64 + db);
      const int dd = b >> 6, tb = b & 63;
      *(bf16x8*)((char*)&v_lds[0][0] + b) =
          *(const bf16x8*)((const char*)vbh + (size_t)dd * (SEQ_ * 2) + t0 * 2 + tb);
    }
    __syncthreads();

    if (t0 <= s0 + 31) {
      const int lb = SEQ_ - 32 - s0 + t0;
      // QEr right half (l_local 32..63); l clamped (clamped rows only feed masked cols)
      f32x4 qerR[2][2] = {};
#pragma unroll
      for (int lt = 0; lt < 2; ++lt)
#pragma unroll
        for (int kc = 0; kc < 2; ++kc) {
          int l = lb + 32 + lt * 16 + r;
          l = l < SEQ_ ? l : SEQ_ - 1;
          bf16x8 ef = *(const bf16x8*)(Er + (size_t)l * DHEAD + kc * 32 + q * 8);
#pragma unroll
          for (int rt = 0; rt < 2; ++rt) qerR[rt][lt] = MFMA(qf[rt][kc], ef, qerR[rt][lt]);
        }
      if (it == 0) {  // first iteration: also compute the left half
#pragma unroll
        for (int rt = 0; rt < 2; ++rt)
#pragma unroll
          for (int lt = 0; lt < 2; ++lt) qerL[rt][lt] = zero4;
#pragma unroll
        for (int lt = 0; lt < 2; ++lt)
#pragma unroll
          for (int kc = 0; kc < 2; ++kc) {
            int l = lb + lt * 16 + r;
            l = l < SEQ_ ? l : SEQ_ - 1;
            bf16x8 ef = *(const bf16x8*)(Er + (size_t)l * DHEAD + kc * 32 + q * 8);
#pragma unroll
            for (int rt = 0; rt < 2; ++rt) qerL[rt][lt] = MFMA(qf[rt][kc], ef, qerL[rt][lt]);
          }
      }
      // write QEr window to LDS (C layout: col=lane&15 -> l_local, row=q*4+reg -> s_local)
#pragma unroll
      for (int rt = 0; rt < 2; ++rt)
#pragma unroll
        for (int lt = 0; lt < 2; ++lt)
#pragma unroll
          for (int j = 0; j < 4; ++j) {
            qer_w[wv][rt * 16 + q * 4 + j][lt * 16 + r]      = qerL[rt][lt][j];
            qer_w[wv][rt * 16 + q * 4 + j][32 + lt * 16 + r] = qerR[rt][lt][j];
          }
#pragma unroll
      for (int rt = 0; rt < 2; ++rt)
#pragma unroll
        for (int lt = 0; lt < 2; ++lt) qerL[rt][lt] = qerR[rt][lt];  // carry right->left

      // QK^T scores
      bf16x8 kf[2][2];
#pragma unroll
      for (int ct = 0; ct < 2; ++ct)
#pragma unroll
        for (int kc = 0; kc < 2; ++kc)
          kf[ct][kc] = *(const bf16x8*)(&k_lds[kc][ct * 16 + r][0] + q * 8);
      f32x4 s4[2][2];
#pragma unroll
      for (int rt = 0; rt < 2; ++rt)
#pragma unroll
        for (int ct = 0; ct < 2; ++ct) {
          f32x4 tacc = MFMA(qf[rt][0], kf[ct][0], zero4);
          s4[rt][ct] = MFMA(qf[rt][1], kf[ct][1], tacc);
        }

      // add gathered Srel, scale, causal mask
      float sv[2][2][4];
#pragma unroll
      for (int rt = 0; rt < 2; ++rt)
#pragma unroll
        for (int ct = 0; ct < 2; ++ct)
#pragma unroll
          for (int j = 0; j < 4; ++j) {
            const int sl = rt * 16 + q * 4 + j;
            const int tl = ct * 16 + r;
            const float srel = qer_w[wv][sl][31 + tl - sl];
            const float val = (s4[rt][ct][j] + srel) * 0.125f;
            sv[rt][ct][j] = (t0 + tl <= s0 + sl) ? val : -1e30f;
          }

      // online softmax (row = 16-lane group; reduce via shfl_xor 1,2,4,8)
#pragma unroll
      for (int rt = 0; rt < 2; ++rt)
#pragma unroll
        for (int j = 0; j < 4; ++j) {
          float mx = fmaxf(sv[rt][0][j], sv[rt][1][j]);
#pragma unroll
          for (int d = 1; d < 16; d <<= 1) mx = fmaxf(mx, __shfl_xor(mx, d));
          const float mold = mrow[rt][j];
          const float mnew = fmaxf(mold, mx);
          const float alpha = __expf(mold - mnew);
          mrow[rt][j] = mnew;
          const float p0 = __expf(sv[rt][0][j] - mnew);
          const float p1 = __expf(sv[rt][1][j] - mnew);
          float ps = p0 + p1;
#pragma unroll
          for (int d = 1; d < 16; d <<= 1) ps += __shfl_xor(ps, d);
          lrow[rt][j] = lrow[rt][j] * alpha + ps;
#pragma unroll
          for (int dc = 0; dc < 4; ++dc) oacc[rt][dc][j] *= alpha;
          const int sl = rt * 16 + q * 4 + j;
          p_lds[wv][sl][r]      = f2bf(p0);
          p_lds[wv][sl][16 + r] = f2bf(p1);
        }

      // PV: A = P rows (t-contiguous via LDS bounce), B = V^T rows d (t-contiguous)
      bf16x8 pf[2], vf[4];
#pragma unroll
      for (int rt = 0; rt < 2; ++rt)
        pf[rt] = *(const bf16x8*)(&p_lds[wv][rt * 16 + r][0] + q * 8);
#pragma unroll
      for (int dc = 0; dc < 4; ++dc)
        vf[dc] = *(const bf16x8*)(&v_lds[dc * 16 + r][0] + q * 8);
#pragma unroll
      for (int rt = 0; rt < 2; ++rt)
#pragma unroll
        for (int dc = 0; dc < 4; ++dc) oacc[rt][dc] = MFMA(pf[rt], vf[dc], oacc[rt][dc]);
    }
    __syncthreads();  // protect k_lds/v_lds before next stage
  }

  // epilogue: divide by softmax denom, store fp32 (b, s, h*64+d)
  const int bb = bh >> 4, hh = bh & 15;
#pragma unroll
  for (int rt = 0; rt < 2; ++rt)
#pragma unroll
    for (int j = 0; j < 4; ++j) {
      const float inv = 1.0f / lrow[rt][j];
      const int ss = s0 + rt * 16 + q * 4 + j;
#pragma unroll
      for (int dc = 0; dc < 4; ++dc) {
        const int dd = dc * 16 + r;
        out[((size_t)(bb * SEQ_ + ss)) * DMODEL + hh * DHEAD + dd] = oacc[rt][dc][j] * inv;
      }
    }
}

// ------------------------------------------------------------------ launch ---
extern "C" void kernel_launch(void* const* d_in, const int* in_sizes, int n_in,
                              void* d_out, int out_size, void* d_ws, size_t ws_size,
                              hipStream_t stream) {
  const float* query = (const float*)d_in[0];
  const float* key   = (const float*)d_in[1];
  const float* value = (const float*)d_in[2];
  const float* Wq    = (const float*)d_in[3];
  const float* bq    = (const float*)d_in[4];
  const float* Wk    = (const float*)d_in[5];
  const float* bk    = (const float*)d_in[6];
  const float* Wv    = (const float*)d_in[7];
  const float* bv    = (const float*)d_in[8];
  const float* Er    = (const float*)d_in[9];

  char* ws = (char*)d_ws;
  unsigned short* qb   = (unsigned short*)(ws + (0u  << 20));  // (B,H,S,64) bf16  8MB
  unsigned short* kbuf = (unsigned short*)(ws + (8u  << 20));  // (B,H,S,64)       8MB
  unsigned short* vTT  = (unsigned short*)(ws + (16u << 20));  // (B,H,64,S)       8MB
  unsigned short* vtmp = (unsigned short*)(ws + (24u << 20));  // (B,H,S,64)       8MB
  unsigned short* Xq   = (unsigned short*)(ws + (32u << 20));  // (B*S, D) bf16    8MB
  unsigned short* Xk   = (unsigned short*)(ws + (40u << 20));
  unsigned short* Xv   = (unsigned short*)(ws + (48u << 20));
  unsigned short* Wqb  = (unsigned short*)(ws + (56u << 20));  // (D, D) bf16      2MB
  unsigned short* Wkb  = (unsigned short*)(ws + (58u << 20));
  unsigned short* Wvb  = (unsigned short*)(ws + (60u << 20));
  unsigned short* Erb  = (unsigned short*)(ws + (62u << 20));  // (2048, 64)     256KB

  conv3_kernel<<<dim3(2048, 3), 256, 0, stream>>>(query, key, value, Xq, Xk, Xv,
                                                  2 * SEQ_ * DMODEL);
  conv3_kernel<<<dim3(512, 3), 256, 0, stream>>>(Wq, Wk, Wv, Wqb, Wkb, Wvb,
                                                 DMODEL * DMODEL);
  conv3_kernel<<<dim3(64, 1), 256, 0, stream>>>(Er, Er, Er, Erb, Erb, Erb,
                                                SEQ_ * DHEAD);

  proj_kernel<<<dim3(32, 8), 256, 0, stream>>>(Xq, Wqb, bq, qb);
  proj_kernel<<<dim3(32, 8), 256, 0, stream>>>(Xk, Wkb, bk, kbuf);
  proj_kernel<<<dim3(32, 8), 256, 0, stream>>>(Xv, Wvb, bv, vtmp);

  transpose_v_kernel<<<dim3(32, 32), 256, 0, stream>>>(vtmp, vTT);

  attn_kernel<<<dim3(16, 32), 256, 0, stream>>>(qb, kbuf, vTT, Erb, (float*)d_out);
}

// Round 2
// 214.623 us; speedup vs baseline: 1.5361x; 1.5361x over previous
//
#include <hip/hip_runtime.h>
#include <hip/hip_bf16.h>

typedef __attribute__((ext_vector_type(8))) short bf16x8;   // 8 bf16 = 4 VGPR (MFMA A/B frag)
typedef __attribute__((ext_vector_type(4))) float f32x4;    // MFMA C/D frag

#define DEVI __device__ __forceinline__

constexpr int SEQ_   = 2048;
constexpr int HEADS  = 16;
constexpr int DHEAD  = 64;
constexpr int DMODEL = 1024;

DEVI unsigned short f2bf(float x) {
  __hip_bfloat16 h = __float2bfloat16(x);   // RNE
  return __builtin_bit_cast(unsigned short, h);
}

DEVI f32x4 MFMA(bf16x8 a, bf16x8 b, f32x4 c) {
  return __builtin_amdgcn_mfma_f32_16x16x32_bf16(a, b, c, 0, 0, 0);
}

// ---------------------------------------------------------------- convert ---
__global__ void conv3_kernel(const float* s0, const float* s1, const float* s2,
                             unsigned short* d0, unsigned short* d1, unsigned short* d2,
                             int n) {
  const float* s = (blockIdx.y == 0) ? s0 : (blockIdx.y == 1) ? s1 : s2;
  unsigned short* d = (blockIdx.y == 0) ? d0 : (blockIdx.y == 1) ? d1 : d2;
  int i = (blockIdx.x * 256 + threadIdx.x) * 8;
  if (i >= n) return;
  const float4* p = (const float4*)(s + i);
  float4 v0 = p[0], v1 = p[1];
  union { unsigned short u[8]; bf16x8 v; } t;
  t.u[0] = f2bf(v0.x); t.u[1] = f2bf(v0.y); t.u[2] = f2bf(v0.z); t.u[3] = f2bf(v0.w);
  t.u[4] = f2bf(v1.x); t.u[5] = f2bf(v1.y); t.u[6] = f2bf(v1.z); t.u[7] = f2bf(v1.w);
  *(bf16x8*)(d + i) = t.v;
}

// ------------------------------------------------------------- projection ---
__global__ __launch_bounds__(256) void proj_kernel(const unsigned short* __restrict__ X,
                                                   const unsigned short* __restrict__ W,
                                                   const float* __restrict__ bias,
                                                   unsigned short* __restrict__ out) {
  __shared__ unsigned short Abuf[2][128 * 32];
  __shared__ unsigned short Bbuf[2][128 * 32];
  const int tid  = threadIdx.x;
  const int lane = tid & 63, wv = tid >> 6;
  const int q = lane >> 4, r = lane & 15;
  const int wrow = wv >> 1, wcol = wv & 1;
  const int rowA0 = blockIdx.x * 128, colB0 = blockIdx.y * 128;

  const char* Ag = (const char*)(X + (size_t)rowA0 * DMODEL);
  const char* Bg = (const char*)(W + (size_t)colB0 * DMODEL);

  f32x4 acc[4][4] = {};

  auto stage = [&](int ks, int buf) {
    const int koff = ks * 64;
#pragma unroll
    for (int i = 0; i < 2; ++i) {
      const int b   = (i * 256 + tid) * 16;
      const int row = b >> 6, col = b & 63;
      __builtin_amdgcn_global_load_lds(
          (const __attribute__((address_space(1))) void*)(Ag + (size_t)row * (DMODEL * 2) + koff + col),
          (__attribute__((address_space(3))) void*)((char*)&Abuf[buf][0] + i * 4096 + wv * 1024),
          16, 0, 0);
      __builtin_amdgcn_global_load_lds(
          (const __attribute__((address_space(1))) void*)(Bg + (size_t)row * (DMODEL * 2) + koff + col),
          (__attribute__((address_space(3))) void*)((char*)&Bbuf[buf][0] + i * 4096 + wv * 1024),
          16, 0, 0);
    }
  };

  stage(0, 0);
  for (int ks = 0; ks < 32; ++ks) {
    __syncthreads();
    if (ks + 1 < 32) stage(ks + 1, (ks + 1) & 1);
    const unsigned short* A  = &Abuf[ks & 1][0];
    const unsigned short* Bt = &Bbuf[ks & 1][0];
    bf16x8 af[4], bfr[4];
#pragma unroll
    for (int t = 0; t < 4; ++t) {
      af[t]  = *(const bf16x8*)(A  + (wrow * 64 + t * 16 + r) * 32 + q * 8);
      bfr[t] = *(const bf16x8*)(Bt + (wcol * 64 + t * 16 + r) * 32 + q * 8);
    }
#pragma unroll
    for (int m = 0; m < 4; ++m)
#pragma unroll
      for (int n = 0; n < 4; ++n)
        acc[m][n] = MFMA(af[m], bfr[n], acc[m][n]);
  }

#pragma unroll
  for (int m = 0; m < 4; ++m) {
#pragma unroll
    for (int n = 0; n < 4; ++n) {
      const int e  = colB0 + wcol * 64 + n * 16 + r;
      const float bv = bias[e];
      const int h = e >> 6, dd = e & 63;
#pragma unroll
      for (int j = 0; j < 4; ++j) {
        const int nrow = rowA0 + wrow * 64 + m * 16 + q * 4 + j;
        const int bb = nrow >> 11, ss = nrow & 2047;
        out[((size_t)(bb * HEADS + h) * SEQ_ + ss) * DHEAD + dd] = f2bf(acc[m][n][j] + bv);
      }
    }
  }
}

// -------------------------------------------------------------- transpose ---
__global__ __launch_bounds__(256) void transpose_v_kernel(const unsigned short* __restrict__ vin,
                                                          unsigned short* __restrict__ vout) {
  __shared__ unsigned short t[64][65];
  const int s0 = blockIdx.x * 64;
  const unsigned short* src = vin  + (size_t)blockIdx.y * SEQ_ * DHEAD + (size_t)s0 * DHEAD;
  unsigned short*       dst = vout + (size_t)blockIdx.y * DHEAD * SEQ_ + s0;
  const int row = threadIdx.x >> 2, seg = (threadIdx.x & 3) * 16;
  unsigned short val[16];
  *(bf16x8*)&val[0] = *(const bf16x8*)(src + row * 64 + seg);
  *(bf16x8*)&val[8] = *(const bf16x8*)(src + row * 64 + seg + 8);
#pragma unroll
  for (int j = 0; j < 16; ++j) t[row][seg + j] = val[j];
  __syncthreads();
#pragma unroll
  for (int j = 0; j < 16; ++j) val[j] = t[seg + j][row];
  *(bf16x8*)(dst + (size_t)row * SEQ_ + seg)     = *(bf16x8*)&val[0];
  *(bf16x8*)(dst + (size_t)row * SEQ_ + seg + 8) = *(bf16x8*)&val[8];
}

// -------------------------------------------------------------- attention ---
// 1024 blocks x 256 thr (4 waves). Wave wv owns 16 q-rows: s0 = qtile*64 + wv*16.
// Block swizzle: xcd = lid&7 -> bh in {4*xcd..4*xcd+3} (K/V 2MB pinned per XCD L2),
// qtile big-first. Per iter (KVB=32): double-buffered reg->LDS K/V staging
// (XOR-swizzled), 1 barrier, Er direct-global, Srel skew-gather via __shfl.
__global__ __launch_bounds__(256, 4) void attn_kernel(const unsigned short* __restrict__ qb,
                                                      const unsigned short* __restrict__ kb,
                                                      const unsigned short* __restrict__ vT,
                                                      const unsigned short* __restrict__ Er,
                                                      float* __restrict__ out) {
  __shared__ unsigned short k_sw[2][32 * 64];   // [t][d] 128B rows, slot^=(row&7)
  __shared__ unsigned short v_sw[2][64 * 32];   // [d][t] 64B rows,  slot^=((row>>1)&3)
  __shared__ unsigned short p_lds[4][16][40];   // per-wave P bounce, 80B stride (2-way, free)

  const int tid  = threadIdx.x;
  const int lane = tid & 63, wv = tid >> 6;
  const int q = lane >> 4, r = lane & 15;

  const int lid = blockIdx.x;
  const int xcd = lid & 7, idx = lid >> 3;
  const int qtile = 31 - (idx >> 2);            // big tiles dispatched first
  const int bh = (xcd << 2) | (idx & 3);
  const int s0 = qtile * 64 + wv * 16;

  const unsigned short* qbh = qb + (size_t)bh * SEQ_ * DHEAD;
  const unsigned short* kbh = kb + (size_t)bh * SEQ_ * DHEAD;
  const unsigned short* vbh = vT + (size_t)bh * DHEAD * SEQ_;

  const f32x4 zero4 = {0.f, 0.f, 0.f, 0.f};

  // A-operand Q fragments (row = r, k = kc*32 + q*8)
  bf16x8 qf0 = *(const bf16x8*)(qbh + (size_t)(s0 + r) * DHEAD + q * 8);
  bf16x8 qf1 = *(const bf16x8*)(qbh + (size_t)(s0 + r) * DHEAD + 32 + q * 8);

  f32x4 oacc[4] = {};
  f32x4 qer0 = zero4, qer1, qer2;
  float mrow[4], lrow[4];
#pragma unroll
  for (int j = 0; j < 4; ++j) { mrow[j] = -1e30f; lrow[j] = 0.f; }

  const int nIter = 2 * qtile + 2;

  // staging geometry (reg -> swizzled LDS; write perm == read perm, rule #21)
  const int krow = tid >> 3, kslot = tid & 7;                    // K: [32][128B]
  unsigned short* kdst = &k_sw[0][0] + krow * 64 + (((kslot ^ (krow & 7)) << 3));
  const int vrow = tid >> 2, vslot = tid & 3;                    // V: [64][64B]
  unsigned short* vdst = &v_sw[0][0] + vrow * 32 + (((vslot ^ ((vrow >> 1) & 3)) << 3));

  bf16x8 kreg = *(const bf16x8*)(kbh + (size_t)krow * DHEAD + kslot * 8);   // tile 0
  bf16x8 vreg = *(const bf16x8*)(vbh + (size_t)vrow * SEQ_ + vslot * 8);

  for (int it = 0; it < nIter; ++it) {
    const int t0 = it * 32;
    const int bsel = it & 1;
    // write staged tile (loaded last iter), then issue next tile's loads (T14)
    *(bf16x8*)(kdst + bsel * (32 * 64)) = kreg;
    *(bf16x8*)(vdst + bsel * (64 * 32)) = vreg;
    if (it + 1 < nIter) {
      const int tn = t0 + 32;
      kreg = *(const bf16x8*)(kbh + (size_t)(tn + krow) * DHEAD + kslot * 8);
      vreg = *(const bf16x8*)(vbh + (size_t)vrow * SEQ_ + tn + vslot * 8);
    }

    const bool active = (t0 <= s0 + 15);
    const int lbase = 2032 + t0 - s0;  // window col 0 -> Er row lbase (>=0)
    // Er B-frags for the 2 (3 at it==0) fresh QEr tiles — global, issued pre-barrier
    bf16x8 e10, e11, e20, e21, e00, e01;
    if (active) {
      int l1 = lbase + 16 + r; l1 = l1 < 2047 ? l1 : 2047;
      int l2 = lbase + 32 + r; l2 = l2 < 2047 ? l2 : 2047;
      e10 = *(const bf16x8*)(Er + (size_t)l1 * DHEAD + q * 8);
      e11 = *(const bf16x8*)(Er + (size_t)l1 * DHEAD + 32 + q * 8);
      e20 = *(const bf16x8*)(Er + (size_t)l2 * DHEAD + q * 8);
      e21 = *(const bf16x8*)(Er + (size_t)l2 * DHEAD + 32 + q * 8);
      if (it == 0) {
        int l0 = lbase + r;
        e00 = *(const bf16x8*)(Er + (size_t)l0 * DHEAD + q * 8);
        e01 = *(const bf16x8*)(Er + (size_t)l0 * DHEAD + 32 + q * 8);
      }
    }
    __syncthreads();

    if (active) {
      // QEr fresh tiles (window cols 16..47); carry: prev T2 -> T0 (cols 0..15)
      qer1 = MFMA(qf1, e11, MFMA(qf0, e10, zero4));
      qer2 = MFMA(qf1, e21, MFMA(qf0, e20, zero4));
      if (it == 0) qer0 = MFMA(qf1, e01, MFMA(qf0, e00, zero4));

      // QK^T: 16 q-rows x 32 t-cols
      f32x4 s4[2];
#pragma unroll
      for (int ct = 0; ct < 2; ++ct) {
        const int row = ct * 16 + r;
        const unsigned short* kbase = &k_sw[bsel][0] + row * 64;
        bf16x8 kf0 = *(const bf16x8*)(kbase + ((q ^ (row & 7)) << 3));
        bf16x8 kf1 = *(const bf16x8*)(kbase + (((4 + q) ^ (row & 7)) << 3));
        s4[ct] = MFMA(qf1, kf1, MFMA(qf0, kf0, zero4));
      }

      // softmax rows sl = q*4+j; cols spread over 16-lane r-group
#pragma unroll
      for (int j = 0; j < 4; ++j) {
        const int sl = q * 4 + j;
        const int idxw = r + 15 - sl;                 // window col for ct=0 (0..30)
        const int srcl = (q << 4) | (idxw & 15);
        const float a0 = __shfl(qer0[j], srcl);
        const float b0 = __shfl(qer1[j], srcl);
        const float a1 = __shfl(qer1[j], srcl);
        const float b1 = __shfl(qer2[j], srcl);
        const bool lo = (idxw < 16);
        float sv0 = (s4[0][j] + (lo ? a0 : b0)) * 0.125f;
        float sv1 = (s4[1][j] + (lo ? a1 : b1)) * 0.125f;
        if (t0 + r      > s0 + sl) sv0 = -1e30f;      // causal
        if (t0 + 16 + r > s0 + sl) sv1 = -1e30f;

        float mx = fmaxf(sv0, sv1);
#pragma unroll
        for (int d = 1; d < 16; d <<= 1) mx = fmaxf(mx, __shfl_xor(mx, d));
        const float mold = mrow[j];
        const float mnew = fmaxf(mold, mx);
        const float alpha = __expf(mold - mnew);
        mrow[j] = mnew;
        const float p0 = __expf(sv0 - mnew);
        const float p1 = __expf(sv1 - mnew);
        float ps = p0 + p1;
#pragma unroll
        for (int d = 1; d < 16; d <<= 1) ps += __shfl_xor(ps, d);
        lrow[j] = lrow[j] * alpha + ps;
#pragma unroll
        for (int dc = 0; dc < 4; ++dc) oacc[dc][j] *= alpha;
        p_lds[wv][sl][r]      = f2bf(p0);
        p_lds[wv][sl][16 + r] = f2bf(p1);
      }

      // PV: A = P (16x32, LDS bounce), B = V^T rows d (t-contiguous, swizzled)
      bf16x8 pf = *(const bf16x8*)(&p_lds[wv][r][0] + q * 8);
#pragma unroll
      for (int dc = 0; dc < 4; ++dc) {
        const int row = dc * 16 + r;
        bf16x8 vf = *(const bf16x8*)(&v_sw[bsel][0] + row * 32 + ((q ^ ((row >> 1) & 3)) << 3));
        oacc[dc] = MFMA(pf, vf, oacc[dc]);
      }
      qer0 = qer2;  // carry window
    }
  }

  // epilogue: normalize, store fp32 (b, s, h*64+d)
  const int bb = bh >> 4, hh = bh & 15;
#pragma unroll
  for (int j = 0; j < 4; ++j) {
    const float inv = 1.0f / lrow[j];
    const int ss = s0 + q * 4 + j;
#pragma unroll
    for (int dc = 0; dc < 4; ++dc) {
      const int dd = dc * 16 + r;
      out[((size_t)(bb * SEQ_ + ss)) * DMODEL + hh * DHEAD + dd] = oacc[dc][j] * inv;
    }
  }
}

// ------------------------------------------------------------------ launch ---
extern "C" void kernel_launch(void* const* d_in, const int* in_sizes, int n_in,
                              void* d_out, int out_size, void* d_ws, size_t ws_size,
                              hipStream_t stream) {
  const float* query = (const float*)d_in[0];
  const float* key   = (const float*)d_in[1];
  const float* value = (const float*)d_in[2];
  const float* Wq    = (const float*)d_in[3];
  const float* bq    = (const float*)d_in[4];
  const float* Wk    = (const float*)d_in[5];
  const float* bk    = (const float*)d_in[6];
  const float* Wv    = (const float*)d_in[7];
  const float* bv    = (const float*)d_in[8];
  const float* Er    = (const float*)d_in[9];

  char* ws = (char*)d_ws;
  unsigned short* qb   = (unsigned short*)(ws + (0u  << 20));  // (B,H,S,64) bf16  8MB
  unsigned short* kbuf = (unsigned short*)(ws + (8u  << 20));  // (B,H,S,64)       8MB
  unsigned short* vTT  = (unsigned short*)(ws + (16u << 20));  // (B,H,64,S)       8MB
  unsigned short* vtmp = (unsigned short*)(ws + (24u << 20));  // (B,H,S,64)       8MB
  unsigned short* Xq   = (unsigned short*)(ws + (32u << 20));  // (B*S, D) bf16    8MB
  unsigned short* Xk   = (unsigned short*)(ws + (40u << 20));
  unsigned short* Xv   = (unsigned short*)(ws + (48u << 20));
  unsigned short* Wqb  = (unsigned short*)(ws + (56u << 20));  // (D, D) bf16      2MB
  unsigned short* Wkb  = (unsigned short*)(ws + (58u << 20));
  unsigned short* Wvb  = (unsigned short*)(ws + (60u << 20));
  unsigned short* Erb  = (unsigned short*)(ws + (62u << 20));  // (2048, 64)     256KB

  conv3_kernel<<<dim3(2048, 3), 256, 0, stream>>>(query, key, value, Xq, Xk, Xv,
                                                  2 * SEQ_ * DMODEL);
  conv3_kernel<<<dim3(512, 3), 256, 0, stream>>>(Wq, Wk, Wv, Wqb, Wkb, Wvb,
                                                 DMODEL * DMODEL);
  conv3_kernel<<<dim3(64, 1), 256, 0, stream>>>(Er, Er, Er, Erb, Erb, Erb,
                                                SEQ_ * DHEAD);

  proj_kernel<<<dim3(32, 8), 256, 0, stream>>>(Xq, Wqb, bq, qb);
  proj_kernel<<<dim3(32, 8), 256, 0, stream>>>(Xk, Wkb, bk, kbuf);
  proj_kernel<<<dim3(32, 8), 256, 0, stream>>>(Xv, Wvb, bv, vtmp);

  transpose_v_kernel<<<dim3(32, 32), 256, 0, stream>>>(vtmp, vTT);

  attn_kernel<<<dim3(1024), 256, 0, stream>>>(qb, kbuf, vTT, Erb, (float*)d_out);
}